// Round 21
// baseline (137.356 us; speedup 1.0000x reference)
//
#include <hip/hip_runtime.h>
#include <stdint.h>

typedef __attribute__((ext_vector_type(4)))  float    f32x4;
typedef __attribute__((ext_vector_type(16))) float    f32x16;
typedef __attribute__((ext_vector_type(8)))  _Float16 f16x8;
typedef __attribute__((ext_vector_type(8)))  __bf16   bf16x8;

#define SEQ   2048
#define DH    64
#define BQ    128            // q rows per block (4 q-waves x 32)
#define BK    64             // keys per tile
#define NT    (SEQ / BK)     // 32 k-tiles per batch
#define HNT   (NT / 2)       // 16 tiles per key-half (split-K factor 2)
#define ROWE  72             // padded row: 144 B stride (16B-aligned, proven 0-conflict)
#define L2E   1.44269504088896340736f

#if __has_builtin(__builtin_amdgcn_exp2f)
static __device__ __forceinline__ float fast_exp2(float x) { return __builtin_amdgcn_exp2f(x); }
#else
static __device__ __forceinline__ float fast_exp2(float x) {
  float r; asm("v_exp_f32 %0, %1" : "=v"(r) : "v"(x)); return r;
}
#endif
static __device__ __forceinline__ uint32_t pack2_bf16(float a, float b) {
  union { __bf16 h[2]; uint32_t u; } cv;
  cv.h[0] = (__bf16)a; cv.h[1] = (__bf16)b;
  return cv.u;
}
union frag_u { uint32_t u[4]; bf16x8 v; };

// sigma relabel (HW-verified): C-layout row m of S^T=K*Q^T carries key sigma(m).
__host__ __device__ inline int sigma32(int m) {
  int b = m & 3, h = (m >> 2) & 1, c = m >> 3;
  return ((c & 1) << 4) | (h << 3) | ((c >> 1) << 2) | b;
}

// ---------------- fused v19: v18 (single kernel, per-block in-LDS conversion,
// no atomics) with ONE change: convWrite(buf^1) moves from after-PV (right
// before the barrier -> 16 waves converge with 6 outstanding LDS writes each,
// lgkmcnt(0)+barrier drain serializes) to after-QK: QK's ~500cyc of MFMA cover
// the load latency, exp+PV's ~2000cyc drain the writes before the barrier.
__global__ __launch_bounds__(512, 2)
void flash_attn_v19(const float* __restrict__ Q, const float* __restrict__ K,
                    const float* __restrict__ V, float* __restrict__ O) {
  __shared__ _Float16 Ksb[2][2][64][ROWE];   // [key-half][dbuf] 36864 B
  __shared__ __bf16   Vtb[2][2][64][ROWE];   // 36864 B
  __shared__ float    Ls[4][32];             // per-qwave 1/rowsum broadcast

  const int tid  = threadIdx.x;
  const int wv   = tid >> 6;             // 0..7
  const int qw   = wv & 3;               // q-wave: which 32 q-rows
  const int kh   = wv >> 2;              // key-half: 0 -> tiles 0..15, 1 -> 16..31
  const int lane = tid & 63;
  const int hfw  = lane >> 5;
  const int l31  = lane & 31;

  const int batch = blockIdx.x & 31;     // batch-major: 16 q-blocks share an XCD
  const int qblk  = blockIdx.x >> 5;

  const float* Qb = Q + (size_t)batch * SEQ * DH;
  const float* Kr = K + (size_t)batch * SEQ * DH;   // raw fp32 K (L2-resident)
  const float* Vr = V + (size_t)batch * SEQ * DH;   // raw fp32 V (L2-resident)
  float*       Ob = O + (size_t)batch * SEQ * DH;

  // ---- per-thread conversion geometry (constant across tiles; prepass math)
  const int t8    = qw * 64 + lane;          // 0..255 within this key-half
  const int krow  = t8 >> 2;                 // K: LDS row this thread fills
  const int kc    = (t8 & 3) << 4;           // K: d-offset (16 elems)
  const int ksrow = (krow & 32) | sigma32(krow & 31);   // sigma'd source row
  const float* kbase = Kr + (size_t)ksrow * DH + kc;

  // K loads: 4x f32x4 from one sigma'd row (64B, L2-hit).
  // V loads: 16 scalar f32, d=lane coalesced across the wave (256B/instr).
  auto convLoad = [&](int t, f32x4* kx, float (*vx)[4]) {
    const float* kp = kbase + (size_t)t * 64 * DH;
#pragma unroll
    for (int u = 0; u < 4; ++u) kx[u] = *(const f32x4*)(kp + 4 * u);
    const float* vp0 = Vr + (size_t)t * 64 * DH + lane;
#pragma unroll
    for (int it = 0; it < 4; ++it) {
      const float* vp = vp0 + (size_t)(4 * (qw + 4 * it)) * DH;
#pragma unroll
      for (int j = 0; j < 4; ++j) vx[it][j] = vp[(size_t)j * DH];
    }
  };
  // cvt + LDS write (identical output bytes to the old prepass tiles)
  auto convWrite = [&](int buf, const f32x4* kx, const float (*vx)[4]) {
    f16x8 h0, h1;
#pragma unroll
    for (int j = 0; j < 4; ++j) {
      h0[j] = (_Float16)kx[0][j]; h0[j + 4] = (_Float16)kx[1][j];
      h1[j] = (_Float16)kx[2][j]; h1[j + 4] = (_Float16)kx[3][j];
    }
    *(f16x8*)&Ksb[kh][buf][krow][kc]     = h0;
    *(f16x8*)&Ksb[kh][buf][krow][kc + 8] = h1;
#pragma unroll
    for (int it = 0; it < 4; ++it) {
      __bf16 hv[4];
#pragma unroll
      for (int j = 0; j < 4; ++j) hv[j] = (__bf16)vx[it][j];
      *(uint64_t*)&Vtb[kh][buf][lane][4 * (qw + 4 * it)] = *(uint64_t*)hv;
    }
  };

  // Q fragments (B-operand of S^T): lane holds Q[q=l31][d=ks*16+hfw*8+j], *log2e
  const int qrow = qblk * BQ + qw * 32 + l31;
  f16x8 qf[4];
  {
    const float* qp = Qb + (size_t)qrow * DH + hfw * 8;
#pragma unroll
    for (int ks = 0; ks < 4; ++ks) {
      f32x4 a = *(const f32x4*)(qp + ks * 16);
      f32x4 b = *(const f32x4*)(qp + ks * 16 + 4);
#pragma unroll
      for (int j = 0; j < 4; ++j) {
        qf[ks][j]     = (_Float16)(a[j] * L2E);
        qf[ks][j + 4] = (_Float16)(b[j] * L2E);
      }
    }
  }

  f32x16 acc0 = {}, acc1 = {};   // O partial: col = d = l31 / l31+32, rows = q
  float lsum = 0.f;              // partial row-sum for q = l31 over this half's keys

  const int t0 = kh * HNT;

  // prologue: convert tile t0 into buf0
  f32x4 kx[4]; float vx[4][4];
  convLoad(t0, kx, vx);
  convWrite(0, kx, vx);

#pragma unroll 1
  for (int li = 0; li < HNT; ++li) {
    __syncthreads();   // buf(li&1) fully written by all converters of this half
    const int buf = li & 1;
    if (li + 1 < HNT) convLoad(t0 + li + 1, kx, vx);   // issue early (T14)

    // ---- S^T = K·Q^T (sigma-relabeled K rows): C col = q = l31, rows = keys
    __builtin_amdgcn_s_setprio(1);
    f32x16 s0 = {}, s1 = {};
#pragma unroll
    for (int ks = 0; ks < 4; ++ks) {
      int dof = ks * 16 + hfw * 8;
      f16x8 kf0 = *(const f16x8*)&Ksb[kh][buf][l31][dof];
      f16x8 kf1 = *(const f16x8*)&Ksb[kh][buf][l31 + 32][dof];
      s0 = __builtin_amdgcn_mfma_f32_32x32x16_f16(kf0, qf[ks], s0, 0, 0, 0);  // keys 0..31
      s1 = __builtin_amdgcn_mfma_f32_32x32x16_f16(kf1, qf[ks], s1, 0, 0, 0);  // keys 32..63
    }
    __builtin_amdgcn_s_setprio(0);

    // ---- conversion write for tile i+1 (buf^1): placed HERE so QK covered the
    // load latency and exp+PV (~2000cyc) drain the LDS writes before the barrier
    if (li + 1 < HNT) convWrite(buf ^ 1, kx, vx);

    // ---- P = exp2(S); repack into natural-key-order A-fragments (registers)
    frag_u fr[4];
#pragma unroll
    for (int t2 = 0; t2 < 2; ++t2) {
      const f32x16& s = t2 ? s1 : s0;
      float p[16];
#pragma unroll
      for (int j = 0; j < 16; ++j) p[j] = fast_exp2(s[j]);
      float a0 = (p[0] + p[1]) + (p[2] + p[3]);
      float a1 = (p[4] + p[5]) + (p[6] + p[7]);
      float a2 = (p[8] + p[9]) + (p[10] + p[11]);
      float a3 = (p[12] + p[13]) + (p[14] + p[15]);
      lsum += (a0 + a1) + (a2 + a3);
      fr[2 * t2    ].u[0] = pack2_bf16(p[0],  p[1]);
      fr[2 * t2    ].u[1] = pack2_bf16(p[2],  p[3]);
      fr[2 * t2    ].u[2] = pack2_bf16(p[8],  p[9]);
      fr[2 * t2    ].u[3] = pack2_bf16(p[10], p[11]);
      fr[2 * t2 + 1].u[0] = pack2_bf16(p[4],  p[5]);
      fr[2 * t2 + 1].u[1] = pack2_bf16(p[6],  p[7]);
      fr[2 * t2 + 1].u[2] = pack2_bf16(p[12], p[13]);
      fr[2 * t2 + 1].u[3] = pack2_bf16(p[14], p[15]);
    }

    // ---- O += P·V : A = P frags (registers), B = V^T (LDS, JIT reads)
    __builtin_amdgcn_s_setprio(1);
#pragma unroll
    for (int ks = 0; ks < 4; ++ks) {
      int kof = ks * 16 + hfw * 8;
      bf16x8 v0 = *(const bf16x8*)&Vtb[kh][buf][l31][kof];
      bf16x8 v1 = *(const bf16x8*)&Vtb[kh][buf][l31 + 32][kof];
      acc0 = __builtin_amdgcn_mfma_f32_32x32x16_bf16(fr[ks].v, v0, acc0, 0, 0, 0);
      acc1 = __builtin_amdgcn_mfma_f32_32x32x16_bf16(fr[ks].v, v1, acc1, 0, 0, 0);
    }
    __builtin_amdgcn_s_setprio(0);
  }

  // ---- split-K combine: exp2-partials are exactly additive. Reuse the dead
  // K/V LDS as the combine buffer (33-stride: lane-major -> conflict-free).
  float tot = lsum + __shfl_xor(lsum, 32);   // this half's full rowsum for q=l31
  __syncthreads();                           // all waves done with tile LDS
  float* cb = (float*)&Ksb[0][0][0][0];      // 4*64*33*4B = 33.8 KB <= 36.8 KB
  float* sb = (float*)&Vtb[0][0][0][0];      // 4*64*4B
  if (kh == 1) {
    const int base = (qw * 64 + lane) * 33;
#pragma unroll
    for (int j = 0; j < 16; ++j) {
      cb[base + j]      = acc0[j];
      cb[base + j + 16] = acc1[j];
    }
    sb[qw * 64 + lane] = tot;
  }
  __syncthreads();
  if (kh == 0) {
    const int base = (qw * 64 + lane) * 33;
    float tot2 = tot + sb[qw * 64 + lane];   // partner half, same q-rows
    Ls[qw][l31] = __builtin_amdgcn_rcpf(tot2);
#pragma unroll
    for (int j = 0; j < 16; ++j) {
      acc0[j] += cb[base + j];
      acc1[j] += cb[base + j + 16];
    }
#pragma unroll
    for (int j = 0; j < 16; ++j) {
      int row = (j & 3) + 8 * (j >> 2) + 4 * hfw;
      float inv = Ls[qw][row];
      size_t off = (size_t)(qblk * BQ + qw * 32 + row) * DH + l31;
      Ob[off]      = acc0[j] * inv;
      Ob[off + 32] = acc1[j] * inv;
    }
  }
}

extern "C" void kernel_launch(void* const* d_in, const int* in_sizes, int n_in,
                              void* d_out, int out_size, void* d_ws, size_t ws_size,
                              hipStream_t stream) {
  (void)in_sizes; (void)n_in; (void)d_ws; (void)ws_size; (void)out_size;
  const float* q = (const float*)d_in[0];
  const float* k = (const float*)d_in[1];
  const float* v = (const float*)d_in[2];
  float* o = (float*)d_out;
  // single fused launch: no prepass, no workspace, no flags
  flash_attn_v19<<<dim3(32 * (SEQ / BQ)), dim3(512), 0, stream>>>(q, k, v, o);
}